// Round 7
// baseline (853.584 us; speedup 1.0000x reference)
//
#include <hip/hip_runtime.h>

// Problem constants (from reference)
#define E_TOT   50000
#define DD      256
#define TE      4               // edges per workgroup
#define NGROUP  (E_TOT / TE)    // 12500
#define SCALE_V 0.125f          // HD^-0.5

#define NHCHUNK 12800000        // E*8*256/8  bf16x8 chunks per h tensor
#define NECHUNK 1600000         // E*256/8    chunks of emb

typedef __attribute__((ext_vector_type(4))) float f32x4;
typedef __attribute__((ext_vector_type(8))) short short8;

__device__ __forceinline__ unsigned short f2bf(float f) {
    unsigned u = __float_as_uint(f);
    u += 0x7fffu + ((u >> 16) & 1u);   // RNE
    return (unsigned short)(u >> 16);
}
__device__ __forceinline__ float gelu_exact(float x) {
    return 0.5f * x * (1.0f + erff(x * 0.70710678118654752440f));
}
__device__ __forceinline__ float sigmoidf(float x) {
    return 1.0f / (1.0f + __expf(-x));
}

// ---------------------------------------------------------------------------
// Kernel P: weights -> bf16 transposed [n][k].
// ---------------------------------------------------------------------------
__global__ void prep_weights(const float* __restrict__ Wq,
                             const float* __restrict__ Wk,
                             const float* __restrict__ We1,
                             unsigned short* __restrict__ wqT,
                             unsigned short* __restrict__ wkT,
                             unsigned short* __restrict__ w1T) {
    int i = blockIdx.x * 256 + threadIdx.x;       // grid 640*256 = 163840
    if (i < 65536) {
        int k = i >> 8, n = i & 255;
        wqT[n * 256 + k] = f2bf(Wq[i]);
    } else if (i < 131072) {
        int j = i - 65536;
        int k = j >> 8, n = j & 255;
        wkT[n * 256 + k] = f2bf(Wk[j]);
    } else {
        int j = i - 131072;                        // 0..32767, [k][n] n<128
        int k = j >> 7, n = j & 127;
        w1T[n * 256 + k] = f2bf(We1[j]);
    }
}

// ---------------------------------------------------------------------------
// Kernel C: streaming h_i/h_j -> bf16 in MFMA-fragment order; emb -> bf16.
// Fragment order: chunk c = g*1024 + ks*128 + m*64 + l holds
//   h[g*32 + m*16 + (l&15)][ks*32 + (l>>4)*8 + j], j=0..7  (bf16x8)
// so the fused kernel's A-fragment load is simply  frag + c*8  (16B/lane,
// consecutive lanes -> consecutive 16B).
// ---------------------------------------------------------------------------
__global__ void conv_frag(const float* __restrict__ hi,
                          const float* __restrict__ hj,
                          const float* __restrict__ emb,
                          unsigned short* __restrict__ fi,
                          unsigned short* __restrict__ fj,
                          unsigned short* __restrict__ ebf) {
    const int nthr = gridDim.x * blockDim.x;
    const int tid  = blockIdx.x * blockDim.x + threadIdx.x;

    for (int c = tid; c < NHCHUNK; c += nthr) {
        const int g  = c >> 10;
        const int r  = c & 1023;
        const int ks = r >> 7, m = (r >> 6) & 1, l = r & 63;
        const size_t row = (size_t)g * 32 + m * 16 + (l & 15);
        const int    col = ks * 32 + (l >> 4) * 8;
        const float* pi = hi + row * DD + col;
        const float* pj = hj + row * DD + col;
        f32x4 a0 = *(const f32x4*)pi;
        f32x4 a1 = *(const f32x4*)(pi + 4);
        f32x4 b0 = *(const f32x4*)pj;
        f32x4 b1 = *(const f32x4*)(pj + 4);
        ushort4 ua0 = make_ushort4(f2bf(a0[0]), f2bf(a0[1]), f2bf(a0[2]), f2bf(a0[3]));
        ushort4 ua1 = make_ushort4(f2bf(a1[0]), f2bf(a1[1]), f2bf(a1[2]), f2bf(a1[3]));
        ushort4 ub0 = make_ushort4(f2bf(b0[0]), f2bf(b0[1]), f2bf(b0[2]), f2bf(b0[3]));
        ushort4 ub1 = make_ushort4(f2bf(b1[0]), f2bf(b1[1]), f2bf(b1[2]), f2bf(b1[3]));
        *(ushort4*)(fi + (size_t)c * 8)     = ua0;
        *(ushort4*)(fi + (size_t)c * 8 + 4) = ua1;
        *(ushort4*)(fj + (size_t)c * 8)     = ub0;
        *(ushort4*)(fj + (size_t)c * 8 + 4) = ub1;
    }
    for (int c = tid; c < NECHUNK; c += nthr) {
        const float* p = emb + (size_t)c * 8;
        f32x4 a0 = *(const f32x4*)p;
        f32x4 a1 = *(const f32x4*)(p + 4);
        *(ushort4*)(ebf + (size_t)c * 8)     =
            make_ushort4(f2bf(a0[0]), f2bf(a0[1]), f2bf(a0[2]), f2bf(a0[3]));
        *(ushort4*)(ebf + (size_t)c * 8 + 4) =
            make_ushort4(f2bf(a1[0]), f2bf(a1[1]), f2bf(a1[2]), f2bf(a1[3]));
    }
}

// ---------------------------------------------------------------------------
// Shared GEMM helpers ([260] pad: measured 0 bank conflicts r4/r5).
// ---------------------------------------------------------------------------
__device__ __forceinline__ void writeback(unsigned short (*T)[260],
                                          const f32x4 acc[2][4],
                                          const float* __restrict__ bias,
                                          int lr, int lq, int w) {
    #pragma unroll
    for (int n = 0; n < 4; ++n) {
        const int col = (w * 4 + n) * 16 + lr;
        const float bs = bias[col];
        #pragma unroll
        for (int m = 0; m < 2; ++m) {
            #pragma unroll
            for (int v = 0; v < 4; ++v) {
                const int row = m * 16 + lq * 4 + v;   // verified C/D layout
                T[row][col] = f2bf(acc[m][n][v] + bs);
            }
        }
    }
}

// ---------------------------------------------------------------------------
// Kernel F: fused, A-fragments straight from global (fragment-order buffers).
// One barrier total.
// ---------------------------------------------------------------------------
__global__ __launch_bounds__(256, 4)
void fused_direct(const float* __restrict__ x_i,
                  const float* __restrict__ x_j,
                  const unsigned short* __restrict__ fi,
                  const unsigned short* __restrict__ fj,
                  const unsigned short* __restrict__ ebf,
                  const unsigned short* __restrict__ wqT,
                  const unsigned short* __restrict__ wkT,
                  const unsigned short* __restrict__ w1T,
                  const float* __restrict__ bq,
                  const float* __restrict__ bk,
                  const float* __restrict__ be1,
                  const float* __restrict__ We2,
                  const float* __restrict__ be2,
                  const float* __restrict__ Wo1,
                  const float* __restrict__ bo1,
                  const float* __restrict__ Wo2,
                  const float* __restrict__ bo2,
                  float* __restrict__ out) {
    __shared__ unsigned short tI[32][260];     // Q tile (bf16)
    __shared__ unsigned short tJ[32][260];     // K tile (bf16)
    __shared__ float sEdgeP[4][4];             // [wave][edge] edge-MLP partials

    const int t  = threadIdx.x;
    const int w  = t >> 6;            // wave 0..3 (owns N-cols w*64..w*64+63)
    const int l  = t & 63;
    const int lr = l & 15, lq = l >> 4;
    const int g  = blockIdx.x;
    const int e  = g * TE + w;

    // ---- cosine partials (reduce deferred) ----
    f32x4 xa = *(const f32x4*)(x_i + (size_t)e * DD + l * 4);
    f32x4 xb = *(const f32x4*)(x_j + (size_t)e * DD + l * 4);
    float cd = xa[0]*xb[0] + xa[1]*xb[1] + xa[2]*xb[2] + xa[3]*xb[3];
    float ci = xa[0]*xa[0] + xa[1]*xa[1] + xa[2]*xa[2] + xa[3]*xa[3];
    float cj = xb[0]*xb[0] + xb[1]*xb[1] + xb[2]*xb[2] + xb[3]*xb[3];

    // ---- Q-GEMM: A-frags direct from fi (all 4 waves same addrs -> L1) ----
    {
        const unsigned short* fb = fi + (size_t)g * 8192;
        f32x4 acc[2][4] = {};
        #pragma unroll
        for (int ks = 0; ks < 8; ++ks) {
            short8 a0 = *(const short8*)(fb + ks * 1024 + l * 8);
            short8 a1 = *(const short8*)(fb + ks * 1024 + 512 + l * 8);
            #pragma unroll
            for (int n = 0; n < 4; ++n) {
                const int col = (w * 4 + n) * 16 + lr;
                short8 bv = *(const short8*)(wqT + col * 256 + ks * 32 + lq * 8);
                acc[0][n] = __builtin_amdgcn_mfma_f32_16x16x32_bf16(a0, bv, acc[0][n], 0, 0, 0);
                acc[1][n] = __builtin_amdgcn_mfma_f32_16x16x32_bf16(a1, bv, acc[1][n], 0, 0, 0);
            }
        }
        writeback(tI, acc, bq, lr, lq, w);     // no barrier needed before first write
    }
    // ---- K-GEMM ----
    {
        const unsigned short* fb = fj + (size_t)g * 8192;
        f32x4 acc[2][4] = {};
        #pragma unroll
        for (int ks = 0; ks < 8; ++ks) {
            short8 a0 = *(const short8*)(fb + ks * 1024 + l * 8);
            short8 a1 = *(const short8*)(fb + ks * 1024 + 512 + l * 8);
            #pragma unroll
            for (int n = 0; n < 4; ++n) {
                const int col = (w * 4 + n) * 16 + lr;
                short8 bv = *(const short8*)(wkT + col * 256 + ks * 32 + lq * 8);
                acc[0][n] = __builtin_amdgcn_mfma_f32_16x16x32_bf16(a0, bv, acc[0][n], 0, 0, 0);
                acc[1][n] = __builtin_amdgcn_mfma_f32_16x16x32_bf16(a1, bv, acc[1][n], 0, 0, 0);
            }
        }
        writeback(tJ, acc, bk, lr, lq, w);
    }
    // ---- edge-MLP GEMM (A-frags from ebf; 4-lane addr dup -> broadcast) ----
    {
        f32x4 accE[2] = {};
        const unsigned short* er = ebf + (size_t)g * 1024 + (lr & 3) * 256;
        #pragma unroll
        for (int ks = 0; ks < 8; ++ks) {
            short8 ae = *(const short8*)(er + ks * 32 + lq * 8);
            #pragma unroll
            for (int n = 0; n < 2; ++n) {
                const int col = w * 32 + n * 16 + lr;
                short8 bv = *(const short8*)(w1T + col * 256 + ks * 32 + lq * 8);
                accE[n] = __builtin_amdgcn_mfma_f32_16x16x32_bf16(ae, bv, accE[n], 0, 0, 0);
            }
        }
        float p[4] = {0.f, 0.f, 0.f, 0.f};
        #pragma unroll
        for (int n = 0; n < 2; ++n) {
            const int col = w * 32 + n * 16 + lr;
            const float b1 = be1[col], w2 = We2[col];
            #pragma unroll
            for (int v = 0; v < 4; ++v)          // C row lq*4+v ≡ edge v
                p[v] += gelu_exact(accE[n][v] + b1) * w2;
        }
        #pragma unroll
        for (int off = 1; off < 16; off <<= 1) {
            #pragma unroll
            for (int v = 0; v < 4; ++v) p[v] += __shfl_xor(p[v], off);
        }
        if (l == 0) {
            sEdgeP[w][0] = p[0]; sEdgeP[w][1] = p[1];
            sEdgeP[w][2] = p[2]; sEdgeP[w][3] = p[3];
        }
    }
    __syncthreads();                           // the single barrier

    // ---- scores: S^T = K·Q^T per head; lane holds S[q=lr&7][4 k-values] ----
    float contrib = 0.f;
    #pragma unroll
    for (int h = 0; h < 4; ++h) {
        f32x4 s = {};
        #pragma unroll
        for (int ks = 0; ks < 2; ++ks) {
            short8 a = *(const short8*)&tJ[w * 8 + (lr & 7)][h * 64 + ks * 32 + lq * 8];
            short8 b = *(const short8*)&tI[w * 8 + (lr & 7)][h * 64 + ks * 32 + lq * 8];
            s = __builtin_amdgcn_mfma_f32_16x16x32_bf16(a, b, s, 0, 0, 0);
        }
        float sc[4];
        #pragma unroll
        for (int v = 0; v < 4; ++v) sc[v] = s[v] * SCALE_V;
        float m4 = fmaxf(fmaxf(sc[0], sc[1]), fmaxf(sc[2], sc[3]));
        float mx = fmaxf(m4, __shfl_xor(m4, 16));
        float pe[4], ps = 0.f;
        #pragma unroll
        for (int v = 0; v < 4; ++v) { pe[v] = __expf(sc[v] - mx); ps += pe[v]; }
        float tot = ps + __shfl_xor(ps, 16);
        float pd = 0.f;
        #pragma unroll
        for (int v = 0; v < 4; ++v)
            pd = (((lq * 4 + v) & 7) == (lr & 7)) ? pe[v] : pd;   // diag k==q
        if (lr < 8 && lq < 2) contrib += pd / tot;
    }

    #pragma unroll
    for (int off = 1; off < 64; off <<= 1) {
        contrib += __shfl_xor(contrib, off);
        cd += __shfl_xor(cd, off);
        ci += __shfl_xor(ci, off);
        cj += __shfl_xor(cj, off);
    }
    const float act  = contrib * (1.0f / 32.0f);
    const float attr = (cd / (fmaxf(sqrtf(ci), 1e-8f) * fmaxf(sqrtf(cj), 1e-8f))
                        + 1.0f) * 0.5f;
    const float es = sigmoidf(sEdgeP[0][w] + sEdgeP[1][w] + sEdgeP[2][w] +
                              sEdgeP[3][w] + be2[0]);

    float r = 0.f;
    if (l < 16) {
        float z = attr * Wo1[l] + act * Wo1[16 + l] + es * Wo1[32 + l] + bo1[l];
        r = gelu_exact(z) * Wo2[l];
    }
    r += __shfl_xor(r, 1);
    r += __shfl_xor(r, 2);
    r += __shfl_xor(r, 4);
    r += __shfl_xor(r, 8);
    if (l == 0) out[e] = sigmoidf(r + bo2[0]);
}

// ---------------------------------------------------------------------------
// Legacy fallback (round-6 kernel) if ws_size is too small for frag buffers.
// ---------------------------------------------------------------------------
__device__ __forceinline__ f32x4 aload(const float* p) {
    f32x4 r;
    asm volatile("global_load_dwordx4 %0, %1, off" : "=v"(r) : "v"(p));
    return r;
}
#define WAITV(N) do { asm volatile("s_waitcnt vmcnt(" #N ")" ::: "memory"); \
                      __builtin_amdgcn_sched_barrier(0); } while (0)

__device__ __forceinline__ void proj_gemm(const unsigned short (*A)[260],
                                          const unsigned short* __restrict__ Wt,
                                          f32x4 acc[2][4], int lr, int lq, int w) {
    #pragma unroll
    for (int ks = 0; ks < 8; ++ks) {
        short8 a0 = *(const short8*)&A[lr][ks * 32 + lq * 8];
        short8 a1 = *(const short8*)&A[16 + lr][ks * 32 + lq * 8];
        #pragma unroll
        for (int n = 0; n < 4; ++n) {
            const int col = (w * 4 + n) * 16 + lr;
            short8 bv = *(const short8*)(Wt + col * 256 + ks * 32 + lq * 8);
            acc[0][n] = __builtin_amdgcn_mfma_f32_16x16x32_bf16(a0, bv, acc[0][n], 0, 0, 0);
            acc[1][n] = __builtin_amdgcn_mfma_f32_16x16x32_bf16(a1, bv, acc[1][n], 0, 0, 0);
        }
    }
}

__global__ __launch_bounds__(256, 3)
void fused_legacy(const float* __restrict__ x_i,
                  const float* __restrict__ x_j,
                  const float* __restrict__ h_i,
                  const float* __restrict__ h_j,
                  const float* __restrict__ emb,
                  const unsigned short* __restrict__ wqT,
                  const unsigned short* __restrict__ wkT,
                  const unsigned short* __restrict__ w1T,
                  const float* __restrict__ bq,
                  const float* __restrict__ bk,
                  const float* __restrict__ be1,
                  const float* __restrict__ We2,
                  const float* __restrict__ be2,
                  const float* __restrict__ Wo1,
                  const float* __restrict__ bo1,
                  const float* __restrict__ Wo2,
                  const float* __restrict__ bo2,
                  float* __restrict__ out) {
    __shared__ unsigned short tI[32][260];
    __shared__ unsigned short tJ[32][260];
    __shared__ float sEmb[TE][DD + 4];
    __shared__ float sEdgeP[4][4];

    const int t  = threadIdx.x;
    const int w  = t >> 6;
    const int l  = t & 63;
    const int lr = l & 15, lq = l >> 4;
    const int g  = blockIdx.x;
    const int e  = g * TE + w;
    const size_t hbase = (size_t)g * (TE * 8 * DD);

    f32x4 si[8], sj[8];
    #pragma unroll
    for (int i = 0; i < 8; ++i)
        si[i] = aload(h_i + hbase + (size_t)(i * 256 + t) * 4);
    #pragma unroll
    for (int i = 0; i < 8; ++i)
        sj[i] = aload(h_j + hbase + (size_t)(i * 256 + t) * 4);
    f32x4 xa = aload(x_i + (size_t)e * DD + l * 4);
    f32x4 xb = aload(x_j + (size_t)e * DD + l * 4);
    f32x4 em = aload(emb + ((size_t)g * TE + (t >> 6)) * DD + (t & 63) * 4);
    __builtin_amdgcn_sched_barrier(0);

    WAITV(11);
    #pragma unroll
    for (int i = 0; i < 8; ++i) {
        const int f = i * 256 + t;
        *(ushort4*)&tI[f >> 6][(f & 63) * 4] =
            make_ushort4(f2bf(si[i][0]), f2bf(si[i][1]), f2bf(si[i][2]), f2bf(si[i][3]));
    }
    WAITV(3);
    #pragma unroll
    for (int i = 0; i < 8; ++i) {
        const int f = i * 256 + t;
        *(ushort4*)&tJ[f >> 6][(f & 63) * 4] =
            make_ushort4(f2bf(sj[i][0]), f2bf(sj[i][1]), f2bf(sj[i][2]), f2bf(sj[i][3]));
    }
    WAITV(0);
    *(f32x4*)&sEmb[t >> 6][(t & 63) * 4] = em;
    float cd = xa[0]*xb[0] + xa[1]*xb[1] + xa[2]*xb[2] + xa[3]*xb[3];
    float ci = xa[0]*xa[0] + xa[1]*xa[1] + xa[2]*xa[2] + xa[3]*xa[3];
    float cj = xb[0]*xb[0] + xb[1]*xb[1] + xb[2]*xb[2] + xb[3]*xb[3];
    __syncthreads();

    f32x4 accE[2] = {};
    #pragma unroll
    for (int ks = 0; ks < 8; ++ks) {
        f32x4 e0 = *(const f32x4*)&sEmb[lr & 3][ks * 32 + lq * 8];
        f32x4 e1 = *(const f32x4*)&sEmb[lr & 3][ks * 32 + lq * 8 + 4];
        short8 ae;
        ae[0] = (short)f2bf(e0[0]); ae[1] = (short)f2bf(e0[1]);
        ae[2] = (short)f2bf(e0[2]); ae[3] = (short)f2bf(e0[3]);
        ae[4] = (short)f2bf(e1[0]); ae[5] = (short)f2bf(e1[1]);
        ae[6] = (short)f2bf(e1[2]); ae[7] = (short)f2bf(e1[3]);
        #pragma unroll
        for (int n = 0; n < 2; ++n) {
            const int col = w * 32 + n * 16 + lr;
            short8 bv = *(const short8*)(w1T + col * 256 + ks * 32 + lq * 8);
            accE[n] = __builtin_amdgcn_mfma_f32_16x16x32_bf16(ae, bv, accE[n], 0, 0, 0);
        }
    }
    {
        f32x4 accQ[2][4] = {};
        proj_gemm(tI, wqT, accQ, lr, lq, w);
        __syncthreads();
        writeback(tI, accQ, bq, lr, lq, w);
    }
    {
        f32x4 accK[2][4] = {};
        proj_gemm(tJ, wkT, accK, lr, lq, w);
        __syncthreads();
        writeback(tJ, accK, bk, lr, lq, w);
    }
    {
        float p[4] = {0.f, 0.f, 0.f, 0.f};
        #pragma unroll
        for (int n = 0; n < 2; ++n) {
            const int col = w * 32 + n * 16 + lr;
            const float b1 = be1[col], w2 = We2[col];
            #pragma unroll
            for (int v = 0; v < 4; ++v)
                p[v] += gelu_exact(accE[n][v] + b1) * w2;
        }
        #pragma unroll
        for (int off = 1; off < 16; off <<= 1) {
            #pragma unroll
            for (int v = 0; v < 4; ++v) p[v] += __shfl_xor(p[v], off);
        }
        if (l == 0) {
            sEdgeP[w][0] = p[0]; sEdgeP[w][1] = p[1];
            sEdgeP[w][2] = p[2]; sEdgeP[w][3] = p[3];
        }
    }
    __syncthreads();

    float contrib = 0.f;
    #pragma unroll
    for (int h = 0; h < 4; ++h) {
        f32x4 s = {};
        #pragma unroll
        for (int ks = 0; ks < 2; ++ks) {
            short8 a = *(const short8*)&tJ[w * 8 + (lr & 7)][h * 64 + ks * 32 + lq * 8];
            short8 b = *(const short8*)&tI[w * 8 + (lr & 7)][h * 64 + ks * 32 + lq * 8];
            s = __builtin_amdgcn_mfma_f32_16x16x32_bf16(a, b, s, 0, 0, 0);
        }
        float sc[4];
        #pragma unroll
        for (int v = 0; v < 4; ++v) sc[v] = s[v] * SCALE_V;
        float m4 = fmaxf(fmaxf(sc[0], sc[1]), fmaxf(sc[2], sc[3]));
        float mx = fmaxf(m4, __shfl_xor(m4, 16));
        float pe[4], ps = 0.f;
        #pragma unroll
        for (int v = 0; v < 4; ++v) { pe[v] = __expf(sc[v] - mx); ps += pe[v]; }
        float tot = ps + __shfl_xor(ps, 16);
        float pd = 0.f;
        #pragma unroll
        for (int v = 0; v < 4; ++v)
            pd = (((lq * 4 + v) & 7) == (lr & 7)) ? pe[v] : pd;
        if (lr < 8 && lq < 2) contrib += pd / tot;
    }
    #pragma unroll
    for (int off = 1; off < 64; off <<= 1) {
        contrib += __shfl_xor(contrib, off);
        cd += __shfl_xor(cd, off);
        ci += __shfl_xor(ci, off);
        cj += __shfl_xor(cj, off);
    }
    const float act  = contrib * (1.0f / 32.0f);
    const float attr = (cd / (fmaxf(sqrtf(ci), 1e-8f) * fmaxf(sqrtf(cj), 1e-8f))
                        + 1.0f) * 0.5f;
    const float es = sigmoidf(sEdgeP[0][w] + sEdgeP[1][w] + sEdgeP[2][w] +
                              sEdgeP[3][w] + be2[0]);
    float r = 0.f;
    if (l < 16) {
        float z = attr * Wo1[l] + act * Wo1[16 + l] + es * Wo1[32 + l] + bo1[l];
        r = gelu_exact(z) * Wo2[l];
    }
    r += __shfl_xor(r, 1);
    r += __shfl_xor(r, 2);
    r += __shfl_xor(r, 4);
    r += __shfl_xor(r, 8);
    if (l == 0) out[e] = sigmoidf(r + bo2[0]);
}

// ---------------------------------------------------------------------------
extern "C" void kernel_launch(void* const* d_in, const int* in_sizes, int n_in,
                              void* d_out, int out_size, void* d_ws, size_t ws_size,
                              hipStream_t stream) {
    const float* x_i  = (const float*)d_in[0];
    const float* x_j  = (const float*)d_in[1];
    const float* h_i  = (const float*)d_in[2];
    const float* h_j  = (const float*)d_in[3];
    const float* emb  = (const float*)d_in[4];
    const float* Wq   = (const float*)d_in[5];
    const float* bq   = (const float*)d_in[6];
    const float* Wk   = (const float*)d_in[7];
    const float* bk   = (const float*)d_in[8];
    const float* We1  = (const float*)d_in[9];
    const float* be1  = (const float*)d_in[10];
    const float* We2  = (const float*)d_in[11];
    const float* be2  = (const float*)d_in[12];
    const float* Wo1  = (const float*)d_in[13];
    const float* bo1  = (const float*)d_in[14];
    const float* Wo2  = (const float*)d_in[15];
    const float* bo2  = (const float*)d_in[16];
    float* out = (float*)d_out;

    // workspace layout
    unsigned short* wqT = (unsigned short*)d_ws;              // 131072 B
    unsigned short* wkT = wqT + 65536;                        // 131072 B
    unsigned short* w1T = wkT + 65536;                        //  65536 B
    unsigned short* ebf = w1T + 32768;                        // 25.6 MB
    unsigned short* fi  = ebf + 12800000;                     // 204.8 MB
    unsigned short* fj  = fi + 102400000;                     // 204.8 MB
    const size_t need = 131072ull + 131072 + 65536 +
                        25600000ull + 204800000ull * 2;

    prep_weights<<<640, 256, 0, stream>>>(Wq, Wk, We1, wqT, wkT, w1T);
    if (ws_size >= need) {
        conv_frag<<<2048, 256, 0, stream>>>(h_i, h_j, emb, fi, fj, ebf);
        fused_direct<<<NGROUP, 256, 0, stream>>>(x_i, x_j, fi, fj, ebf,
                                                 wqT, wkT, w1T,
                                                 bq, bk, be1, We2, be2,
                                                 Wo1, bo1, Wo2, bo2, out);
    } else {
        fused_legacy<<<NGROUP, 256, 0, stream>>>(x_i, x_j, h_i, h_j, emb,
                                                 wqT, wkT, w1T,
                                                 bq, bk, be1, We2, be2,
                                                 Wo1, bo1, Wo2, bo2, out);
    }
}

// Round 8
// 674.839 us; speedup vs baseline: 1.2649x; 1.2649x over previous
//
#include <hip/hip_runtime.h>

// Problem constants (from reference)
#define E_TOT   50000
#define DD      256
#define EPG     8               // edges per workgroup (fused kernel)
#define NWG     (E_TOT / EPG)   // 6250
#define SCALE_V 0.125f          // HD^-0.5

#define NHCHUNK 12800000        // E*8*256/8  bf16x8 chunks per h tensor
#define NECHUNK 1600000         // E*256/8    chunks of emb

typedef __attribute__((ext_vector_type(4))) float f32x4;
typedef __attribute__((ext_vector_type(8))) short short8;

__device__ __forceinline__ unsigned short f2bf(float f) {
    unsigned u = __float_as_uint(f);
    u += 0x7fffu + ((u >> 16) & 1u);   // RNE
    return (unsigned short)(u >> 16);
}
__device__ __forceinline__ float gelu_exact(float x) {
    return 0.5f * x * (1.0f + erff(x * 0.70710678118654752440f));
}
__device__ __forceinline__ float sigmoidf(float x) {
    return 1.0f / (1.0f + __expf(-x));
}

// Async HBM->LDS DMA: wave writes lds_base + lane*16 from g + lane*16.
__device__ __forceinline__ void dma16(const void* g, void* lds) {
    const int lane = threadIdx.x & 63;
    auto gp = (const __attribute__((address_space(1))) char*)g + lane * 16;
    auto lp = (__attribute__((address_space(3))) char*)lds;
    __builtin_amdgcn_global_load_lds(gp, lp, 16, 0, 0);
}

// ---------------------------------------------------------------------------
// Kernel P: weights -> bf16 transposed [n][k].
// ---------------------------------------------------------------------------
__global__ void prep_weights(const float* __restrict__ Wq,
                             const float* __restrict__ Wk,
                             const float* __restrict__ We1,
                             unsigned short* __restrict__ wqT,
                             unsigned short* __restrict__ wkT,
                             unsigned short* __restrict__ w1T) {
    int i = blockIdx.x * 256 + threadIdx.x;       // grid 640*256 = 163840
    if (i < 65536) {
        int k = i >> 8, n = i & 255;
        wqT[n * 256 + k] = f2bf(Wq[i]);
    } else if (i < 131072) {
        int j = i - 65536;
        int k = j >> 8, n = j & 255;
        wkT[n * 256 + k] = f2bf(Wk[j]);
    } else {
        int j = i - 131072;                        // 0..32767, [k][n] n<128
        int k = j >> 7, n = j & 127;
        w1T[n * 256 + k] = f2bf(We1[j]);
    }
}

// ---------------------------------------------------------------------------
// Kernel C: streaming h_i/h_j -> bf16 in MFMA-fragment order; emb -> bf16.
// Chunk c = g*1024 + ks*128 + m*64 + l  (g = 32-row group) holds
//   h[g*32 + m*16 + (l&15)][ks*32 + (l>>4)*8 + j], j=0..7 (bf16x8).
// Measured (r7): this kernel runs at ~5.8 TB/s.
// ---------------------------------------------------------------------------
__global__ void conv_frag(const float* __restrict__ hi,
                          const float* __restrict__ hj,
                          const float* __restrict__ emb,
                          unsigned short* __restrict__ fi,
                          unsigned short* __restrict__ fj,
                          unsigned short* __restrict__ ebf) {
    const int nthr = gridDim.x * blockDim.x;
    const int tid  = blockIdx.x * blockDim.x + threadIdx.x;

    for (int c = tid; c < NHCHUNK; c += nthr) {
        const int g  = c >> 10;
        const int r  = c & 1023;
        const int ks = r >> 7, m = (r >> 6) & 1, l = r & 63;
        const size_t row = (size_t)g * 32 + m * 16 + (l & 15);
        const int    col = ks * 32 + (l >> 4) * 8;
        const float* pi = hi + row * DD + col;
        const float* pj = hj + row * DD + col;
        f32x4 a0 = *(const f32x4*)pi;
        f32x4 a1 = *(const f32x4*)(pi + 4);
        f32x4 b0 = *(const f32x4*)pj;
        f32x4 b1 = *(const f32x4*)(pj + 4);
        *(ushort4*)(fi + (size_t)c * 8)     =
            make_ushort4(f2bf(a0[0]), f2bf(a0[1]), f2bf(a0[2]), f2bf(a0[3]));
        *(ushort4*)(fi + (size_t)c * 8 + 4) =
            make_ushort4(f2bf(a1[0]), f2bf(a1[1]), f2bf(a1[2]), f2bf(a1[3]));
        *(ushort4*)(fj + (size_t)c * 8)     =
            make_ushort4(f2bf(b0[0]), f2bf(b0[1]), f2bf(b0[2]), f2bf(b0[3]));
        *(ushort4*)(fj + (size_t)c * 8 + 4) =
            make_ushort4(f2bf(b1[0]), f2bf(b1[1]), f2bf(b1[2]), f2bf(b1[3]));
    }
    for (int c = tid; c < NECHUNK; c += nthr) {
        const float* p = emb + (size_t)c * 8;
        f32x4 a0 = *(const f32x4*)p;
        f32x4 a1 = *(const f32x4*)(p + 4);
        *(ushort4*)(ebf + (size_t)c * 8)     =
            make_ushort4(f2bf(a0[0]), f2bf(a0[1]), f2bf(a0[2]), f2bf(a0[3]));
        *(ushort4*)(ebf + (size_t)c * 8 + 4) =
            make_ushort4(f2bf(a1[0]), f2bf(a1[1]), f2bf(a1[2]), f2bf(a1[3]));
    }
}

// ---------------------------------------------------------------------------
// Kernel F: 8 edges/WG. DMA-staged A tiles, 4 barriers, M=64 N=256 K=256.
// ---------------------------------------------------------------------------
__device__ __forceinline__ void writeback4(unsigned short (*T)[260],
                                           const f32x4 acc[4][4],
                                           const float* __restrict__ bias,
                                           int lr, int lq, int w) {
    #pragma unroll
    for (int n = 0; n < 4; ++n) {
        const int col = (w * 4 + n) * 16 + lr;
        const float bs = bias[col];
        #pragma unroll
        for (int m = 0; m < 4; ++m) {
            #pragma unroll
            for (int v = 0; v < 4; ++v) {
                const int row = m * 16 + lq * 4 + v;   // verified C/D layout
                T[row][col] = f2bf(acc[m][n][v] + bs);
            }
        }
    }
}

__global__ __launch_bounds__(256, 2)
void fused_tile(const float* __restrict__ x_i,
                const float* __restrict__ x_j,
                const unsigned short* __restrict__ fi,
                const unsigned short* __restrict__ fj,
                const unsigned short* __restrict__ ebf,
                const unsigned short* __restrict__ wqT,
                const unsigned short* __restrict__ wkT,
                const unsigned short* __restrict__ w1T,
                const float* __restrict__ bq,
                const float* __restrict__ bk,
                const float* __restrict__ be1,
                const float* __restrict__ We2,
                const float* __restrict__ be2,
                const float* __restrict__ Wo1,
                const float* __restrict__ bo1,
                const float* __restrict__ Wo2,
                const float* __restrict__ bo2,
                float* __restrict__ out) {
    // Overlayed LDS (barrier-sequenced reuse):
    //   [0      .. 32768)  fiS staging   -> later tQ [64][260] (0..33280)
    //   [33280  .. 66048)  fjS staging   -> later tK [64][260] (33280..66560)
    __shared__ __align__(16) unsigned char lds[66560 + 128];
    unsigned short (*tQ)[260] = (unsigned short (*)[260])lds;
    unsigned short (*tK)[260] = (unsigned short (*)[260])(lds + 33280);
    unsigned char* fiS = lds;
    unsigned char* fjS = lds + 33280;
    float* sEdgeP = (float*)(lds + 66560);     // [4][8] wave-major partials

    const int t  = threadIdx.x;
    const int w  = t >> 6;            // wave 0..3 (N-cols w*64..w*64+63)
    const int l  = t & 63;
    const int lr = l & 15, lq = l >> 4;
    const int b  = blockIdx.x;

    // ---- phase 0: issue all 16 DMAs (fi+fj 64KB), zero VGPR cost ----
    #pragma unroll
    for (int i = 0; i < 8; ++i)
        dma16((const char*)fi + (size_t)b * 32768 + w * 8192 + i * 1024,
              fiS + w * 8192 + i * 1024);
    #pragma unroll
    for (int i = 0; i < 8; ++i)
        dma16((const char*)fj + (size_t)b * 32768 + w * 8192 + i * 1024,
              fjS + w * 8192 + i * 1024);

    // ---- cosine for this wave's 2 edges (hides DMA latency) ----
    float attr[2];
    #pragma unroll
    for (int ee = 0; ee < 2; ++ee) {
        const int e = b * EPG + 2 * w + ee;
        f32x4 xa = *(const f32x4*)(x_i + (size_t)e * DD + l * 4);
        f32x4 xb = *(const f32x4*)(x_j + (size_t)e * DD + l * 4);
        float cd = xa[0]*xb[0] + xa[1]*xb[1] + xa[2]*xb[2] + xa[3]*xb[3];
        float ci = xa[0]*xa[0] + xa[1]*xa[1] + xa[2]*xa[2] + xa[3]*xa[3];
        float cj = xb[0]*xb[0] + xb[1]*xb[1] + xb[2]*xb[2] + xb[3]*xb[3];
        #pragma unroll
        for (int off = 1; off < 64; off <<= 1) {
            cd += __shfl_xor(cd, off);
            ci += __shfl_xor(ci, off);
            cj += __shfl_xor(cj, off);
        }
        attr[ee] = (cd / (fmaxf(sqrtf(ci), 1e-8f) * fmaxf(sqrtf(cj), 1e-8f))
                    + 1.0f) * 0.5f;
    }

    // ---- edge MLP (8 edges; also hides DMA latency) ----
    {
        f32x4 accE[2] = {};
        const unsigned short* er = ebf + ((size_t)b * EPG + (lr & 7)) * 256;
        #pragma unroll
        for (int ks = 0; ks < 8; ++ks) {
            short8 ae = *(const short8*)(er + ks * 32 + lq * 8);
            #pragma unroll
            for (int n = 0; n < 2; ++n) {
                const int col = w * 32 + n * 16 + lr;
                short8 bv = *(const short8*)(w1T + col * 256 + ks * 32 + lq * 8);
                accE[n] = __builtin_amdgcn_mfma_f32_16x16x32_bf16(ae, bv, accE[n], 0, 0, 0);
            }
        }
        float p[4] = {0.f, 0.f, 0.f, 0.f};
        #pragma unroll
        for (int n = 0; n < 2; ++n) {
            const int col = w * 32 + n * 16 + lr;
            const float b1 = be1[col], w2 = We2[col];
            #pragma unroll
            for (int v = 0; v < 4; ++v)          // C row lq*4+v -> edge (row&7)
                p[v] += gelu_exact(accE[n][v] + b1) * w2;
        }
        #pragma unroll
        for (int off = 1; off < 16; off <<= 1) {
            #pragma unroll
            for (int v = 0; v < 4; ++v) p[v] += __shfl_xor(p[v], off);
        }
        if (l == 0) {          // rows 0..3  = edges 0..3
            sEdgeP[w * 8 + 0] = p[0]; sEdgeP[w * 8 + 1] = p[1];
            sEdgeP[w * 8 + 2] = p[2]; sEdgeP[w * 8 + 3] = p[3];
        }
        if (l == 16) {         // rows 4..7  = edges 4..7
            sEdgeP[w * 8 + 4] = p[0]; sEdgeP[w * 8 + 5] = p[1];
            sEdgeP[w * 8 + 6] = p[2]; sEdgeP[w * 8 + 7] = p[3];
        }
    }
    __syncthreads();                               // B1: DMA landed

    // ---- Q-GEMM: M=64 (4 tiles) x N=64/wave (4 tiles) x K=256 ----
    f32x4 accQ[4][4] = {};
    #pragma unroll
    for (int ks = 0; ks < 8; ++ks) {
        short8 bv[4];
        #pragma unroll
        for (int n = 0; n < 4; ++n)
            bv[n] = *(const short8*)(wqT + ((w * 4 + n) * 16 + lr) * 256 + ks * 32 + lq * 8);
        #pragma unroll
        for (int m = 0; m < 4; ++m) {
            short8 av = *(const short8*)(fiS + (m >> 1) * 16384 + ks * 2048 +
                                         (m & 1) * 1024 + l * 16);
            #pragma unroll
            for (int n = 0; n < 4; ++n)
                accQ[m][n] = __builtin_amdgcn_mfma_f32_16x16x32_bf16(av, bv[n], accQ[m][n], 0, 0, 0);
        }
    }
    __syncthreads();                               // B2: fiS reads done
    writeback4(tQ, accQ, bq, lr, lq, w);           // tQ overlays fiS

    // ---- K-GEMM (reads fjS; disjoint from tQ) ----
    f32x4 accK[4][4] = {};
    #pragma unroll
    for (int ks = 0; ks < 8; ++ks) {
        short8 bv[4];
        #pragma unroll
        for (int n = 0; n < 4; ++n)
            bv[n] = *(const short8*)(wkT + ((w * 4 + n) * 16 + lr) * 256 + ks * 32 + lq * 8);
        #pragma unroll
        for (int m = 0; m < 4; ++m) {
            short8 av = *(const short8*)(fjS + (m >> 1) * 16384 + ks * 2048 +
                                         (m & 1) * 1024 + l * 16);
            #pragma unroll
            for (int n = 0; n < 4; ++n)
                accK[m][n] = __builtin_amdgcn_mfma_f32_16x16x32_bf16(av, bv[n], accK[m][n], 0, 0, 0);
        }
    }
    __syncthreads();                               // B3: fjS reads + tQ writes done
    writeback4(tK, accK, bk, lr, lq, w);           // tK overlays fjS
    __syncthreads();                               // B4: tiles ready

    // ---- scores for this wave's 2 edges (S^T = K·Q^T per head) ----
    float contrib[2] = {0.f, 0.f};
    #pragma unroll
    for (int ee = 0; ee < 2; ++ee) {
        const int rowb = (2 * w + ee) * 8 + (lr & 7);
        #pragma unroll
        for (int h = 0; h < 4; ++h) {
            f32x4 s = {};
            #pragma unroll
            for (int ks = 0; ks < 2; ++ks) {
                short8 a = *(const short8*)&tK[rowb][h * 64 + ks * 32 + lq * 8];
                short8 bb = *(const short8*)&tQ[rowb][h * 64 + ks * 32 + lq * 8];
                s = __builtin_amdgcn_mfma_f32_16x16x32_bf16(a, bb, s, 0, 0, 0);
            }
            // lane holds S[q=lr&7][k=(lq*4+v)&7]
            float sc[4];
            #pragma unroll
            for (int v = 0; v < 4; ++v) sc[v] = s[v] * SCALE_V;
            float m4 = fmaxf(fmaxf(sc[0], sc[1]), fmaxf(sc[2], sc[3]));
            float mx = fmaxf(m4, __shfl_xor(m4, 16));
            float pe[4], ps = 0.f;
            #pragma unroll
            for (int v = 0; v < 4; ++v) { pe[v] = __expf(sc[v] - mx); ps += pe[v]; }
            float tot = ps + __shfl_xor(ps, 16);
            float pd = 0.f;
            #pragma unroll
            for (int v = 0; v < 4; ++v)
                pd = (((lq * 4 + v) & 7) == (lr & 7)) ? pe[v] : pd;   // k==q
            if (lr < 8 && lq < 2) contrib[ee] += pd / tot;
        }
    }
    #pragma unroll
    for (int off = 1; off < 64; off <<= 1) {
        contrib[0] += __shfl_xor(contrib[0], off);
        contrib[1] += __shfl_xor(contrib[1], off);
    }

    // ---- final 3 -> 16 -> 1 MLP, 2 edges/wave ----
    #pragma unroll
    for (int ee = 0; ee < 2; ++ee) {
        const int eloc = 2 * w + ee;
        const float act = contrib[ee] * (1.0f / 32.0f);
        const float es  = sigmoidf(sEdgeP[0 * 8 + eloc] + sEdgeP[1 * 8 + eloc] +
                                   sEdgeP[2 * 8 + eloc] + sEdgeP[3 * 8 + eloc] + be2[0]);
        float r = 0.f;
        if (l < 16) {
            float z = attr[ee] * Wo1[l] + act * Wo1[16 + l] + es * Wo1[32 + l] + bo1[l];
            r = gelu_exact(z) * Wo2[l];
        }
        r += __shfl_xor(r, 1);
        r += __shfl_xor(r, 2);
        r += __shfl_xor(r, 4);
        r += __shfl_xor(r, 8);
        if (l == 0) out[b * EPG + eloc] = sigmoidf(r + bo2[0]);
    }
}

// ---------------------------------------------------------------------------
extern "C" void kernel_launch(void* const* d_in, const int* in_sizes, int n_in,
                              void* d_out, int out_size, void* d_ws, size_t ws_size,
                              hipStream_t stream) {
    const float* x_i  = (const float*)d_in[0];
    const float* x_j  = (const float*)d_in[1];
    const float* h_i  = (const float*)d_in[2];
    const float* h_j  = (const float*)d_in[3];
    const float* emb  = (const float*)d_in[4];
    const float* Wq   = (const float*)d_in[5];
    const float* bq   = (const float*)d_in[6];
    const float* Wk   = (const float*)d_in[7];
    const float* bk   = (const float*)d_in[8];
    const float* We1  = (const float*)d_in[9];
    const float* be1  = (const float*)d_in[10];
    const float* We2  = (const float*)d_in[11];
    const float* be2  = (const float*)d_in[12];
    const float* Wo1  = (const float*)d_in[13];
    const float* bo1  = (const float*)d_in[14];
    const float* Wo2  = (const float*)d_in[15];
    const float* bo2  = (const float*)d_in[16];
    float* out = (float*)d_out;

    // workspace layout (r7-proven size: ~436 MB available)
    unsigned short* wqT = (unsigned short*)d_ws;              // 131072 B
    unsigned short* wkT = wqT + 65536;                        // 131072 B
    unsigned short* w1T = wkT + 65536;                        //  65536 B
    unsigned short* ebf = w1T + 32768;                        // 25.6 MB
    unsigned short* fi  = ebf + 12800000;                     // 204.8 MB
    unsigned short* fj  = fi + 102400000;                     // 204.8 MB

    prep_weights<<<640, 256, 0, stream>>>(Wq, Wk, We1, wqT, wkT, w1T);
    conv_frag<<<2048, 256, 0, stream>>>(h_i, h_j, emb, fi, fj, ebf);
    fused_tile<<<NWG, 256, 0, stream>>>(x_i, x_j, fi, fj, ebf,
                                        wqT, wkT, w1T,
                                        bq, bk, be1, We2, be2,
                                        Wo1, bo1, Wo2, bo2, out);
}